// Round 10
// baseline (170.990 us; speedup 1.0000x reference)
//
#include <hip/hip_runtime.h>
#include <math.h>

#define N_NODES 50000
#define N_EDGES 800000
#define DOUT 64
#define NHEAD 8
#define RP1 9            // num_relations + 1 (self-loop relation id = 8)
#define NEG_SLOPE 0.2f
#define EPS_F 1e-10f
#define M_TOT (N_EDGES + N_NODES)   // 850000 edges incl. self-loops
#define NW (RP1 * DOUT * DOUT)      // 36,864 W elements

// --- two-level bucketing (R23 config restored) ---
#define SUBSH 6                          // 64 nodes per subrange
#define NSUB ((N_NODES + 63) >> SUBSH)   // 782 subranges
#define SEGCAP 1536                      // lambda=1088, sigma~33
#define EPB 4096                         // R25: back to R23 (R24's 2048 regressed)
#define CHUNKS ((M_TOT + EPB - 1) / EPB) // 208 fill blocks
#define K1B ((N_NODES + 63) / 64)        // 782 k1 blocks (R23 64-node version)

typedef __attribute__((ext_vector_type(8))) short bf16x8;
typedef __attribute__((ext_vector_type(4))) float f32x4;

__device__ __forceinline__ unsigned short f2bf(float f) {
    unsigned int u = __float_as_uint(f);
    unsigned int r = (u + 0x7FFFu + ((u >> 16) & 1u)) >> 16;   // RNE
    return (unsigned short)r;
}
__device__ __forceinline__ float bf2f(unsigned short s) {
    return __uint_as_float(((unsigned int)s) << 16);
}

// ===========================================================================
// kprep2: W f32->bf16 + subcursor zeroing only (tiny).
// ===========================================================================
__global__ __launch_bounds__(256) void kprep2(const float* __restrict__ W,
                                              unsigned short* __restrict__ Wb,
                                              int* __restrict__ subcursor) {
    int m = blockIdx.x * 256 + threadIdx.x;
    if (m < NW / 4) {
        int i = m * 4;
        float4 v = *(const float4*)(W + i);
        ushort4 o; o.x = f2bf(v.x); o.y = f2bf(v.y); o.z = f2bf(v.z); o.w = f2bf(v.w);
        *(ushort4*)(Wb + i) = o;
    }
    if (m < NSUB) subcursor[m] = 0;
}

// ===========================================================================
// kbig (R25 = R23 revert, frozen): R24's TLP-doubling REGRESSED kbig 55->63
// despite occupancy 26->37% -- more waves provably don't help this kernel
// (2nd refutation after R21). R23's shape is its empirical best: k1 role =
// 782 blocks x 4 waves x (16 nodes x 64 douts x 9 rels); fill role = 208
// blocks, EPB 4096, two-level span reservation (~162k global atomics).
// ===========================================================================
__global__ __launch_bounds__(256) void kbig(const float* __restrict__ x,
                                            const unsigned short* __restrict__ Wb,
                                            unsigned short* __restrict__ hiddenb,
                                            const int* __restrict__ node_in,
                                            const int* __restrict__ node_out,
                                            const int* __restrict__ relation,
                                            const float* __restrict__ edge_w,
                                            int* __restrict__ subcursor,
                                            int2* __restrict__ seg) {
    __shared__ union SM {
        unsigned short st[4 * 16 * 72];               // k1 role: 9216 B
        struct { int cnt[NSUB]; int base[NSUB]; } f;  // fill role: 6256 B
    } sm;
    const int t = threadIdx.x;

    if (blockIdx.x >= K1B) {
        // ---------------- fill role (two-level, EPB 4096) ----------------
        const int chunk = blockIdx.x - K1B;
        const int m0 = chunk * EPB;
        for (int s2 = t; s2 < NSUB; s2 += 256) sm.f.cnt[s2] = 0;
        __syncthreads();
        // pass 1: per-subrange count (LDS atomics, coalesced node_out read)
#pragma unroll
        for (int it = 0; it < EPB / 256; it++) {
            int m = m0 + it * 256 + t;
            if (m < M_TOT) {
                int no = (m < N_EDGES) ? node_out[m] : (m - N_EDGES);
                atomicAdd(&sm.f.cnt[no >> SUBSH], 1);
            }
        }
        __syncthreads();
        // reserve spans: one global atomic per non-empty subrange
        for (int s2 = t; s2 < NSUB; s2 += 256) {
            int c = sm.f.cnt[s2];
            sm.f.base[s2] = (c > 0) ? atomicAdd(&subcursor[s2], c) : 0;
        }
        __syncthreads();
        for (int s2 = t; s2 < NSUB; s2 += 256) sm.f.cnt[s2] = 0;
        __syncthreads();
        // pass 2: scatter into spans (edge arrays L2-hot from pass 1)
#pragma unroll
        for (int it = 0; it < EPB / 256; it++) {
            int m = m0 + it * 256 + t;
            if (m < M_TOT) {
                int no, ni, rl; float ew;
                if (m < N_EDGES) {
                    no = node_out[m]; ni = node_in[m];
                    rl = relation[m]; ew = edge_w[m];
                } else {
                    no = m - N_EDGES; ni = no; rl = RP1 - 1; ew = 1.0f;
                }
                int s2 = no >> SUBSH;
                int r = atomicAdd(&sm.f.cnt[s2], 1);
                int pos = sm.f.base[s2] + r;
                if (pos < SEGCAP) {
                    int2 v;
                    v.x = ni | (rl << 16) | ((no & 63) << 20);
                    v.y = __float_as_int(ew);
                    seg[(size_t)s2 * SEGCAP + pos] = v;
                }
            }
        }
        return;
    }

    // ---------------- k1 (MFMA) role (R23 body) ----------------
    const int bx = blockIdx.x;
    const int wv = t >> 6, lane = t & 63;
    const int quad = lane >> 4, l16 = lane & 15;
    const int base = bx * 64 + wv * 16;

    int arow = base + l16;
    if (arow >= N_NODES) arow = N_NODES - 1;
    const float* xr = x + (size_t)arow * 64 + quad * 8;
    const float4 f0 = *(const float4*)(xr + 0);
    const float4 f1 = *(const float4*)(xr + 4);
    const float4 f2 = *(const float4*)(xr + 32);
    const float4 f3 = *(const float4*)(xr + 36);
    bf16x8 a0, a1;
    a0[0] = (short)f2bf(f0.x); a0[1] = (short)f2bf(f0.y);
    a0[2] = (short)f2bf(f0.z); a0[3] = (short)f2bf(f0.w);
    a0[4] = (short)f2bf(f1.x); a0[5] = (short)f2bf(f1.y);
    a0[6] = (short)f2bf(f1.z); a0[7] = (short)f2bf(f1.w);
    a1[0] = (short)f2bf(f2.x); a1[1] = (short)f2bf(f2.y);
    a1[2] = (short)f2bf(f2.z); a1[3] = (short)f2bf(f2.w);
    a1[4] = (short)f2bf(f3.x); a1[5] = (short)f2bf(f3.y);
    a1[6] = (short)f2bf(f3.z); a1[7] = (short)f2bf(f3.w);

    unsigned short* sw = &sm.st[wv * 16 * 72];

    for (int r = 0; r < RP1; r++) {
        const unsigned short* Wr = Wb + r * 4096;
        f32x4 acc[4];
#pragma unroll
        for (int dt = 0; dt < 4; dt++) {
            const bf16x8 b0 = *(const bf16x8*)(Wr + (dt * 16 + l16) * 64 + quad * 8);
            const bf16x8 b1 = *(const bf16x8*)(Wr + (dt * 16 + l16) * 64 + quad * 8 + 32);
            f32x4 c = {0.f, 0.f, 0.f, 0.f};
            c = __builtin_amdgcn_mfma_f32_16x16x32_bf16(a0, b0, c, 0, 0, 0);
            c = __builtin_amdgcn_mfma_f32_16x16x32_bf16(a1, b1, c, 0, 0, 0);
            acc[dt] = c;
        }
#pragma unroll
        for (int dt = 0; dt < 4; dt++) {
#pragma unroll
            for (int v = 0; v < 4; v++) {
                sw[(quad * 4 + v) * 72 + dt * 16 + l16] = f2bf(acc[dt][v]);
            }
        }
        __threadfence_block();
#pragma unroll
        for (int q = 0; q < 2; q++) {
            int cid = q * 64 + lane;
            int row = cid >> 3;
            int ch = cid & 7;
            int n = base + row;
            if (n < N_NODES) {
                bf16x8 v = *(const bf16x8*)(sw + row * 72 + ch * 8);
                *(bf16x8*)(hiddenb + ((size_t)r * N_NODES + n) * 64 + ch * 8) = v;
            }
        }
        __threadfence_block();
    }
}

// ===========================================================================
// k3_seg (R25): HALF-SUBRANGE blocks. R22/R23 counters: occupancy 26% -- the
// 782-block grid itself caps waves at 6.1/SIMD; k3's random-gather latency
// needs TLP it can actually use (unlike kbig -- R21/R24 refuted that there).
// Now 2 blocks per subrange: each register-stages the full segment, counts/
// sorts ONLY its 32-node half (filter on bit 5 of local node id), computes
// 2 pairs/wave. Grid 782 -> 1564, waves 6256 -> 12512 (12.2/SIMD); per-block
// serial chain halves. Cost: seg read 2x (+9.6 MB, coalesced).
// ===========================================================================
__global__ __launch_bounds__(512) void k3_seg(const unsigned short* __restrict__ hiddenb,
                                              const float* __restrict__ query,
                                              const int2* __restrict__ seg,
                                              const int* __restrict__ subcursor,
                                              float* __restrict__ out) {
    __shared__ float qe[RP1 * 64];
    __shared__ float qo[RP1 * 64];
    __shared__ int2  smeta[SEGCAP];
    __shared__ int cnt[32], start[32], cnt2[32];
    __shared__ float bho[8][2][72];

    const int t = threadIdx.x;
    const int s = blockIdx.x >> 1;
    const int half = blockIdx.x & 1;
    const int scnt = min(subcursor[s], SEGCAP);

    // ---- stage this subrange's seg entries in registers (early) ----
    const int i0 = t, i1 = t + 512, i2 = t + 1024;
    int2 ev0, ev1, ev2;
    if (i0 < scnt) ev0 = seg[(size_t)s * SEGCAP + i0];
    if (i1 < scnt) ev1 = seg[(size_t)s * SEGCAP + i1];
    if (i2 < scnt) ev2 = seg[(size_t)s * SEGCAP + i2];

    for (int q = t; q < RP1 * 64; q += 512) {
        int j = q & 7, rh = q >> 3;
        qe[q] = query[rh * 16 + 2 * j];
        qo[q] = query[rh * 16 + 2 * j + 1];
    }
    if (t < 32) { cnt[t] = 0; cnt2[t] = 0; }
    __syncthreads();

    // count only entries belonging to this half (local nodes half*32..+31)
    int nl0 = -1, nl1 = -1, nl2 = -1;
    if (i0 < scnt) { int nl = (ev0.x >> 20) & 63; if ((nl >> 5) == half) nl0 = nl & 31; }
    if (i1 < scnt) { int nl = (ev1.x >> 20) & 63; if ((nl >> 5) == half) nl1 = nl & 31; }
    if (i2 < scnt) { int nl = (ev2.x >> 20) & 63; if ((nl >> 5) == half) nl2 = nl & 31; }
    if (nl0 >= 0) atomicAdd(&cnt[nl0], 1);
    if (nl1 >= 0) atomicAdd(&cnt[nl1], 1);
    if (nl2 >= 0) atomicAdd(&cnt[nl2], 1);
    __syncthreads();

    if (t < 32) {                       // exclusive prefix scan of cnt (32)
        int v = cnt[t];
        int sc = v;
#pragma unroll
        for (int d = 1; d < 32; d <<= 1) {
            int o = __shfl_up(sc, d);
            if (t >= d) sc += o;
        }
        start[t] = sc - v;
    }
    __syncthreads();

    if (nl0 >= 0) smeta[start[nl0] + atomicAdd(&cnt2[nl0], 1)] = ev0;
    if (nl1 >= 0) smeta[start[nl1] + atomicAdd(&cnt2[nl1], 1)] = ev1;
    if (nl2 >= 0) smeta[start[nl2] + atomicAdd(&cnt2[nl2], 1)] = ev2;
    __syncthreads();

    const int wv = t >> 6, lane = t & 63;
    const int e_lo = lane >> 3, h = lane & 7;
    const int prel = lane >> 3, ph = lane & 7;

    for (int k = 0; k < 2; k++) {
        const int nAl = (k * 8 + wv) * 2, nBl = nAl + 1;   // local 0..31
        const int nA = (s << SUBSH) + half * 32 + nAl, nB = nA + 1;
        if (nA >= N_NODES) continue;            // wave-uniform (last subrange)

        // ---- per-pair prologue: h_out . q_odd for all 9 rels ----
        {
            const bf16x8 ra = *(const bf16x8*)(hiddenb + ((size_t)(prel * N_NODES + nA)) * 64 + ph * 8);
            const bf16x8 rb = *(const bf16x8*)(hiddenb + ((size_t)(prel * N_NODES + nB)) * 64 + ph * 8);
            bf16x8 r8 = ra;
            if (lane < 16) {
                int n8 = (lane < 8) ? nA : nB;
                r8 = *(const bf16x8*)(hiddenb + ((size_t)(8 * N_NODES + n8)) * 64 + (lane & 7) * 8);
            }
            const float* qop = &qo[(prel * 8 + ph) * 8];
            float da = 0.f, db = 0.f;
#pragma unroll
            for (int j = 0; j < 8; j++) {
                da += qop[j] * bf2f((unsigned short)ra[j]);
                db += qop[j] * bf2f((unsigned short)rb[j]);
            }
            bho[wv][0][prel * 8 + ph] = da;
            bho[wv][1][prel * 8 + ph] = db;
            if (lane < 16) {
                const float* q8p = &qo[(64 + (lane & 7)) * 8];
                float d8 = 0.f;
#pragma unroll
                for (int j = 0; j < 8; j++) d8 += q8p[j] * bf2f((unsigned short)r8[j]);
                bho[wv][(lane < 8) ? 0 : 1][64 + (lane & 7)] = d8;
            }
        }
        __threadfence_block();

        const int cA = cnt[nAl], cB = cnt[nBl];
        const int stA = start[nAl], stB = start[nBl];
        const float degA = (float)cA, degB = (float)cB;
        const int cM = (cA > cB) ? cA : cB;

        float accA[8] = {0.f, 0.f, 0.f, 0.f, 0.f, 0.f, 0.f, 0.f};
        float accB[8] = {0.f, 0.f, 0.f, 0.f, 0.f, 0.f, 0.f, 0.f};
        float spA = 0.f, spB = 0.f;

        for (int j0 = 0; j0 < cM; j0 += 32) {
            bf16x8 rA[4], rB[4];
            int relA[4], relB[4]; float ewA[4], ewB[4];
#pragma unroll
            for (int p = 0; p < 4; p++) {
                const int sa = j0 + p * 8 + e_lo;
                if (sa < cA) {
                    int2 mv = smeta[stA + sa];
                    int ni = mv.x & 0xffff;
                    int rl = min((mv.x >> 16) & 15, RP1 - 1);   // defensive clamp
                    relA[p] = rl; ewA[p] = __int_as_float(mv.y);
                    rA[p] = *(const bf16x8*)(hiddenb + ((size_t)(rl * N_NODES + ni)) * 64 + h * 8);
                }
                if (sa < cB) {
                    int2 mv = smeta[stB + sa];
                    int ni = mv.x & 0xffff;
                    int rl = min((mv.x >> 16) & 15, RP1 - 1);   // defensive clamp
                    relB[p] = rl; ewB[p] = __int_as_float(mv.y);
                    rB[p] = *(const bf16x8*)(hiddenb + ((size_t)(rl * N_NODES + ni)) * 64 + h * 8);
                }
            }
#pragma unroll
            for (int p = 0; p < 4; p++) {
                const int sa = j0 + p * 8 + e_lo;
                if (sa < cA) {
                    const float* qp = &qe[(relA[p] * 8 + h) * 8];
                    float hif[8];
#pragma unroll
                    for (int j = 0; j < 8; j++) hif[j] = bf2f((unsigned short)rA[p][j]);
                    float wp = bho[wv][0][relA[p] * 8 + h];
#pragma unroll
                    for (int j = 0; j < 8; j++) wp += qp[j] * hif[j];
                    wp = (wp > 0.f) ? wp : NEG_SLOPE * wp;
                    float pa = __expf(wp) * ewA[p];
#pragma unroll
                    for (int j = 0; j < 8; j++) accA[j] += pa * hif[j];
                    spA += pa;
                }
                if (sa < cB) {
                    const float* qp = &qe[(relB[p] * 8 + h) * 8];
                    float hif[8];
#pragma unroll
                    for (int j = 0; j < 8; j++) hif[j] = bf2f((unsigned short)rB[p][j]);
                    float wp = bho[wv][1][relB[p] * 8 + h];
#pragma unroll
                    for (int j = 0; j < 8; j++) wp += qp[j] * hif[j];
                    wp = (wp > 0.f) ? wp : NEG_SLOPE * wp;
                    float pa = __expf(wp) * ewB[p];
#pragma unroll
                    for (int j = 0; j < 8; j++) accB[j] += pa * hif[j];
                    spB += pa;
                }
            }
        }

#pragma unroll
        for (int j = 0; j < 8; j++) {
            accA[j] += __shfl_xor(accA[j], 8);
            accA[j] += __shfl_xor(accA[j], 16);
            accA[j] += __shfl_xor(accA[j], 32);
            accB[j] += __shfl_xor(accB[j], 8);
            accB[j] += __shfl_xor(accB[j], 16);
            accB[j] += __shfl_xor(accB[j], 32);
        }
        spA += __shfl_xor(spA, 8); spA += __shfl_xor(spA, 16); spA += __shfl_xor(spA, 32);
        spB += __shfl_xor(spB, 8); spB += __shfl_xor(spB, 16); spB += __shfl_xor(spB, 32);

        if (lane < 8) {
            const float sc = 1.f / ((spA / degA + EPS_F) * degA);
            float4 o0, o1;
            o0.x = fmaxf(accA[0] * sc, 0.f); o0.y = fmaxf(accA[1] * sc, 0.f);
            o0.z = fmaxf(accA[2] * sc, 0.f); o0.w = fmaxf(accA[3] * sc, 0.f);
            o1.x = fmaxf(accA[4] * sc, 0.f); o1.y = fmaxf(accA[5] * sc, 0.f);
            o1.z = fmaxf(accA[6] * sc, 0.f); o1.w = fmaxf(accA[7] * sc, 0.f);
            float* op = out + (size_t)nA * 64 + lane * 8;
            *(float4*)(op) = o0; *(float4*)(op + 4) = o1;
        } else if (lane < 16) {
            const float sc = 1.f / ((spB / degB + EPS_F) * degB);
            float4 o0, o1;
            o0.x = fmaxf(accB[0] * sc, 0.f); o0.y = fmaxf(accB[1] * sc, 0.f);
            o0.z = fmaxf(accB[2] * sc, 0.f); o0.w = fmaxf(accB[3] * sc, 0.f);
            o1.x = fmaxf(accB[4] * sc, 0.f); o1.y = fmaxf(accB[5] * sc, 0.f);
            o1.z = fmaxf(accB[6] * sc, 0.f); o1.w = fmaxf(accB[7] * sc, 0.f);
            float* op = out + (size_t)nB * 64 + (lane - 8) * 8;
            *(float4*)(op) = o0; *(float4*)(op + 4) = o1;
        }
    }
}

extern "C" void kernel_launch(void* const* d_in, const int* in_sizes, int n_in,
                              void* d_out, int out_size, void* d_ws, size_t ws_size,
                              hipStream_t stream) {
    const float* x        = (const float*)d_in[0];
    const float* W_tau    = (const float*)d_in[1];
    const float* query    = (const float*)d_in[2];
    const int*   node_in  = (const int*)d_in[3];
    const int*   node_out = (const int*)d_in[4];
    const int*   relation = (const int*)d_in[5];
    const float* edge_w   = (const float*)d_in[6];
    float* out = (float*)d_out;

    char* ws = (char*)d_ws;
    unsigned short* hiddenb   = (unsigned short*)(ws);                // 57,600,000
    unsigned short* Wb        = (unsigned short*)(ws + 57600000);     //     73,728
    int2*           seg       = (int2*)(ws + 57673728);               //  9,609,216
    int*            subcursor = (int*)(ws + 67282944);                //      3,128

    // W conversion + subcursor zeroing (tiny)
    kprep2<<<(NW / 4 + 255) / 256, 256, 0, stream>>>(W_tau, Wb, subcursor);

    // merged (R23 shape, frozen): MFMA transform overlapped with two-level fill
    kbig<<<K1B + CHUNKS, 256, 0, stream>>>(x, Wb, hiddenb, node_in, node_out,
                                           relation, edge_w, subcursor, seg);

    // per-HALF-subrange: register-staged physical sort + fused logits/agg/relu
    k3_seg<<<NSUB * 2, 512, 0, stream>>>(hiddenb, query, seg, subcursor, out);
}

// Round 11
// 165.616 us; speedup vs baseline: 1.0325x; 1.0325x over previous
//
#include <hip/hip_runtime.h>
#include <math.h>

#define N_NODES 50000
#define N_EDGES 800000
#define DOUT 64
#define NHEAD 8
#define RP1 9            // num_relations + 1 (self-loop relation id = 8)
#define NEG_SLOPE 0.2f
#define EPS_F 1e-10f
#define M_TOT (N_EDGES + N_NODES)   // 850000 edges incl. self-loops
#define NW (RP1 * DOUT * DOUT)      // 36,864 W elements

// --- two-level bucketing (R23 config) ---
#define SUBSH 6                          // 64 nodes per subrange
#define NSUB ((N_NODES + 63) >> SUBSH)   // 782 subranges
#define SEGCAP 1536                      // lambda=1088, sigma~33
#define EPB 4096                         // per fill chunk (R23 value)
#define CHUNKS ((M_TOT + EPB - 1) / EPB) // 208 fill blocks
#define K1B ((N_NODES + 127) / 128)      // R26: 391 k1 blocks (128 nodes, 8 waves)

typedef __attribute__((ext_vector_type(8))) short bf16x8;
typedef __attribute__((ext_vector_type(4))) float f32x4;

__device__ __forceinline__ unsigned short f2bf(float f) {
    unsigned int u = __float_as_uint(f);
    unsigned int r = (u + 0x7FFFu + ((u >> 16) & 1u)) >> 16;   // RNE
    return (unsigned short)r;
}
__device__ __forceinline__ float bf2f(unsigned short s) {
    return __uint_as_float(((unsigned int)s) << 16);
}

// ===========================================================================
// kprep2: W f32->bf16 + subcursor zeroing only (tiny).
// ===========================================================================
__global__ __launch_bounds__(256) void kprep2(const float* __restrict__ W,
                                              unsigned short* __restrict__ Wb,
                                              int* __restrict__ subcursor) {
    int m = blockIdx.x * 256 + threadIdx.x;
    if (m < NW / 4) {
        int i = m * 4;
        float4 v = *(const float4*)(W + i);
        ushort4 o; o.x = f2bf(v.x); o.y = f2bf(v.y); o.z = f2bf(v.z); o.w = f2bf(v.w);
        *(ushort4*)(Wb + i) = o;
    }
    if (m < NSUB) subcursor[m] = 0;
}

// ===========================================================================
// kbig (R26): R23 bodies at 512 threads/block. The ONLY change vs R23 is
// block width -- no extra traffic, atomics, or staging (the overhead that
// sank R21/R24/R25's TLP attempts):
//   fill role: 8 waves/block, EPB 4096 -> per-pass dependent chain halves
//     (16 -> 8 iterations); same 208 chunks, same ~162k reserve atomics.
//   k1 role:   8 waves x 16 nodes = 128 nodes/block (2 R23 blocks fused);
//     per-wave work identical, K1B 782 -> 391.
// Pre-committed reading: kbig <50 confirms fill-chain latency hypothesis;
// kbig >=55 refutes it -> kbig's floor is elsewhere (scatter-store drain).
// ===========================================================================
__global__ __launch_bounds__(512) void kbig(const float* __restrict__ x,
                                            const unsigned short* __restrict__ Wb,
                                            unsigned short* __restrict__ hiddenb,
                                            const int* __restrict__ node_in,
                                            const int* __restrict__ node_out,
                                            const int* __restrict__ relation,
                                            const float* __restrict__ edge_w,
                                            int* __restrict__ subcursor,
                                            int2* __restrict__ seg) {
    __shared__ union SM {
        unsigned short st[8 * 16 * 72];               // k1 role: 18432 B
        struct { int cnt[NSUB]; int base[NSUB]; } f;  // fill role: 6256 B
    } sm;
    const int t = threadIdx.x;

    if (blockIdx.x >= K1B) {
        // ---------------- fill role (two-level, 8 waves) ----------------
        const int chunk = blockIdx.x - K1B;
        const int m0 = chunk * EPB;
        for (int s2 = t; s2 < NSUB; s2 += 512) sm.f.cnt[s2] = 0;
        __syncthreads();
        // pass 1: per-subrange count (LDS atomics, coalesced node_out read)
#pragma unroll
        for (int it = 0; it < EPB / 512; it++) {
            int m = m0 + it * 512 + t;
            if (m < M_TOT) {
                int no = (m < N_EDGES) ? node_out[m] : (m - N_EDGES);
                atomicAdd(&sm.f.cnt[no >> SUBSH], 1);
            }
        }
        __syncthreads();
        // reserve spans: one global atomic per non-empty subrange
        for (int s2 = t; s2 < NSUB; s2 += 512) {
            int c = sm.f.cnt[s2];
            sm.f.base[s2] = (c > 0) ? atomicAdd(&subcursor[s2], c) : 0;
        }
        __syncthreads();
        for (int s2 = t; s2 < NSUB; s2 += 512) sm.f.cnt[s2] = 0;
        __syncthreads();
        // pass 2: scatter into spans (edge arrays L2-hot from pass 1)
#pragma unroll
        for (int it = 0; it < EPB / 512; it++) {
            int m = m0 + it * 512 + t;
            if (m < M_TOT) {
                int no, ni, rl; float ew;
                if (m < N_EDGES) {
                    no = node_out[m]; ni = node_in[m];
                    rl = relation[m]; ew = edge_w[m];
                } else {
                    no = m - N_EDGES; ni = no; rl = RP1 - 1; ew = 1.0f;
                }
                int s2 = no >> SUBSH;
                int r = atomicAdd(&sm.f.cnt[s2], 1);
                int pos = sm.f.base[s2] + r;
                if (pos < SEGCAP) {
                    int2 v;
                    v.x = ni | (rl << 16) | ((no & 63) << 20);
                    v.y = __float_as_int(ew);
                    seg[(size_t)s2 * SEGCAP + pos] = v;
                }
            }
        }
        return;
    }

    // ---------------- k1 (MFMA) role (R23 body, 8 waves/block) --------------
    const int bx = blockIdx.x;
    const int wv = t >> 6, lane = t & 63;
    const int quad = lane >> 4, l16 = lane & 15;
    const int base = bx * 128 + wv * 16;

    int arow = base + l16;
    if (arow >= N_NODES) arow = N_NODES - 1;
    const float* xr = x + (size_t)arow * 64 + quad * 8;
    const float4 f0 = *(const float4*)(xr + 0);
    const float4 f1 = *(const float4*)(xr + 4);
    const float4 f2 = *(const float4*)(xr + 32);
    const float4 f3 = *(const float4*)(xr + 36);
    bf16x8 a0, a1;
    a0[0] = (short)f2bf(f0.x); a0[1] = (short)f2bf(f0.y);
    a0[2] = (short)f2bf(f0.z); a0[3] = (short)f2bf(f0.w);
    a0[4] = (short)f2bf(f1.x); a0[5] = (short)f2bf(f1.y);
    a0[6] = (short)f2bf(f1.z); a0[7] = (short)f2bf(f1.w);
    a1[0] = (short)f2bf(f2.x); a1[1] = (short)f2bf(f2.y);
    a1[2] = (short)f2bf(f2.z); a1[3] = (short)f2bf(f2.w);
    a1[4] = (short)f2bf(f3.x); a1[5] = (short)f2bf(f3.y);
    a1[6] = (short)f2bf(f3.z); a1[7] = (short)f2bf(f3.w);

    unsigned short* sw = &sm.st[wv * 16 * 72];

    for (int r = 0; r < RP1; r++) {
        const unsigned short* Wr = Wb + r * 4096;
        f32x4 acc[4];
#pragma unroll
        for (int dt = 0; dt < 4; dt++) {
            const bf16x8 b0 = *(const bf16x8*)(Wr + (dt * 16 + l16) * 64 + quad * 8);
            const bf16x8 b1 = *(const bf16x8*)(Wr + (dt * 16 + l16) * 64 + quad * 8 + 32);
            f32x4 c = {0.f, 0.f, 0.f, 0.f};
            c = __builtin_amdgcn_mfma_f32_16x16x32_bf16(a0, b0, c, 0, 0, 0);
            c = __builtin_amdgcn_mfma_f32_16x16x32_bf16(a1, b1, c, 0, 0, 0);
            acc[dt] = c;
        }
#pragma unroll
        for (int dt = 0; dt < 4; dt++) {
#pragma unroll
            for (int v = 0; v < 4; v++) {
                sw[(quad * 4 + v) * 72 + dt * 16 + l16] = f2bf(acc[dt][v]);
            }
        }
        __threadfence_block();
#pragma unroll
        for (int q = 0; q < 2; q++) {
            int cid = q * 64 + lane;
            int row = cid >> 3;
            int ch = cid & 7;
            int n = base + row;
            if (n < N_NODES) {
                bf16x8 v = *(const bf16x8*)(sw + row * 72 + ch * 8);
                *(bf16x8*)(hiddenb + ((size_t)r * N_NODES + n) * 64 + ch * 8) = v;
            }
        }
        __threadfence_block();
    }
}

// ===========================================================================
// k3_seg (R26 = R23 revert): full-subrange 512-thread blocks, register-staged
// physical counting sort + fused logits/aggregation/relu. R25's half-split
// regressed (doubled seg/prologue staging per useful work); R23 is best.
// ===========================================================================
__global__ __launch_bounds__(512) void k3_seg(const unsigned short* __restrict__ hiddenb,
                                              const float* __restrict__ query,
                                              const int2* __restrict__ seg,
                                              const int* __restrict__ subcursor,
                                              float* __restrict__ out) {
    __shared__ float qe[RP1 * 64];
    __shared__ float qo[RP1 * 64];
    __shared__ int2  smeta[SEGCAP];
    __shared__ int cnt[64], start[64], cnt2[64];
    __shared__ float bho[8][2][72];

    const int t = threadIdx.x;
    const int s = blockIdx.x;
    const int scnt = min(subcursor[s], SEGCAP);

    // ---- stage this block's seg entries in registers (early, independent) --
    const int i0 = t, i1 = t + 512, i2 = t + 1024;
    int2 ev0, ev1, ev2;
    if (i0 < scnt) ev0 = seg[(size_t)s * SEGCAP + i0];
    if (i1 < scnt) ev1 = seg[(size_t)s * SEGCAP + i1];
    if (i2 < scnt) ev2 = seg[(size_t)s * SEGCAP + i2];

    for (int q = t; q < RP1 * 64; q += 512) {
        int j = q & 7, rh = q >> 3;
        qe[q] = query[rh * 16 + 2 * j];
        qo[q] = query[rh * 16 + 2 * j + 1];
    }
    if (t < 64) { cnt[t] = 0; cnt2[t] = 0; }
    __syncthreads();

    if (i0 < scnt) atomicAdd(&cnt[(ev0.x >> 20) & 63], 1);
    if (i1 < scnt) atomicAdd(&cnt[(ev1.x >> 20) & 63], 1);
    if (i2 < scnt) atomicAdd(&cnt[(ev2.x >> 20) & 63], 1);
    __syncthreads();

    if (t < 64) {                       // wave 0: exclusive prefix scan of cnt
        int v = cnt[t];
        int sc = v;
#pragma unroll
        for (int d = 1; d < 64; d <<= 1) {
            int o = __shfl_up(sc, d);
            if (t >= d) sc += o;
        }
        start[t] = sc - v;
    }
    __syncthreads();

    if (i0 < scnt) {
        int nol = (ev0.x >> 20) & 63;
        smeta[start[nol] + atomicAdd(&cnt2[nol], 1)] = ev0;
    }
    if (i1 < scnt) {
        int nol = (ev1.x >> 20) & 63;
        smeta[start[nol] + atomicAdd(&cnt2[nol], 1)] = ev1;
    }
    if (i2 < scnt) {
        int nol = (ev2.x >> 20) & 63;
        smeta[start[nol] + atomicAdd(&cnt2[nol], 1)] = ev2;
    }
    __syncthreads();

    const int wv = t >> 6, lane = t & 63;
    const int e_lo = lane >> 3, h = lane & 7;
    const int prel = lane >> 3, ph = lane & 7;

    for (int k = 0; k < 4; k++) {
        const int nAl = (k * 8 + wv) * 2, nBl = nAl + 1;
        const int nA = (s << SUBSH) + nAl, nB = nA + 1;
        if (nA >= N_NODES) continue;            // wave-uniform (last subrange)

        // ---- per-pair prologue: h_out . q_odd for all 9 rels ----
        {
            const bf16x8 ra = *(const bf16x8*)(hiddenb + ((size_t)(prel * N_NODES + nA)) * 64 + ph * 8);
            const bf16x8 rb = *(const bf16x8*)(hiddenb + ((size_t)(prel * N_NODES + nB)) * 64 + ph * 8);
            bf16x8 r8 = ra;
            if (lane < 16) {
                int n8 = (lane < 8) ? nA : nB;
                r8 = *(const bf16x8*)(hiddenb + ((size_t)(8 * N_NODES + n8)) * 64 + (lane & 7) * 8);
            }
            const float* qop = &qo[(prel * 8 + ph) * 8];
            float da = 0.f, db = 0.f;
#pragma unroll
            for (int j = 0; j < 8; j++) {
                da += qop[j] * bf2f((unsigned short)ra[j]);
                db += qop[j] * bf2f((unsigned short)rb[j]);
            }
            bho[wv][0][prel * 8 + ph] = da;
            bho[wv][1][prel * 8 + ph] = db;
            if (lane < 16) {
                const float* q8p = &qo[(64 + (lane & 7)) * 8];
                float d8 = 0.f;
#pragma unroll
                for (int j = 0; j < 8; j++) d8 += q8p[j] * bf2f((unsigned short)r8[j]);
                bho[wv][(lane < 8) ? 0 : 1][64 + (lane & 7)] = d8;
            }
        }
        __threadfence_block();

        const int cA = cnt[nAl], cB = cnt[nBl];
        const int stA = start[nAl], stB = start[nBl];
        const float degA = (float)cA, degB = (float)cB;
        const int cM = (cA > cB) ? cA : cB;

        float accA[8] = {0.f, 0.f, 0.f, 0.f, 0.f, 0.f, 0.f, 0.f};
        float accB[8] = {0.f, 0.f, 0.f, 0.f, 0.f, 0.f, 0.f, 0.f};
        float spA = 0.f, spB = 0.f;

        for (int j0 = 0; j0 < cM; j0 += 32) {
            bf16x8 rA[4], rB[4];
            int relA[4], relB[4]; float ewA[4], ewB[4];
#pragma unroll
            for (int p = 0; p < 4; p++) {
                const int sa = j0 + p * 8 + e_lo;
                if (sa < cA) {
                    int2 mv = smeta[stA + sa];
                    int ni = mv.x & 0xffff;
                    int rl = min((mv.x >> 16) & 15, RP1 - 1);   // defensive clamp
                    relA[p] = rl; ewA[p] = __int_as_float(mv.y);
                    rA[p] = *(const bf16x8*)(hiddenb + ((size_t)(rl * N_NODES + ni)) * 64 + h * 8);
                }
                if (sa < cB) {
                    int2 mv = smeta[stB + sa];
                    int ni = mv.x & 0xffff;
                    int rl = min((mv.x >> 16) & 15, RP1 - 1);   // defensive clamp
                    relB[p] = rl; ewB[p] = __int_as_float(mv.y);
                    rB[p] = *(const bf16x8*)(hiddenb + ((size_t)(rl * N_NODES + ni)) * 64 + h * 8);
                }
            }
#pragma unroll
            for (int p = 0; p < 4; p++) {
                const int sa = j0 + p * 8 + e_lo;
                if (sa < cA) {
                    const float* qp = &qe[(relA[p] * 8 + h) * 8];
                    float hif[8];
#pragma unroll
                    for (int j = 0; j < 8; j++) hif[j] = bf2f((unsigned short)rA[p][j]);
                    float wp = bho[wv][0][relA[p] * 8 + h];
#pragma unroll
                    for (int j = 0; j < 8; j++) wp += qp[j] * hif[j];
                    wp = (wp > 0.f) ? wp : NEG_SLOPE * wp;
                    float pa = __expf(wp) * ewA[p];
#pragma unroll
                    for (int j = 0; j < 8; j++) accA[j] += pa * hif[j];
                    spA += pa;
                }
                if (sa < cB) {
                    const float* qp = &qe[(relB[p] * 8 + h) * 8];
                    float hif[8];
#pragma unroll
                    for (int j = 0; j < 8; j++) hif[j] = bf2f((unsigned short)rB[p][j]);
                    float wp = bho[wv][1][relB[p] * 8 + h];
#pragma unroll
                    for (int j = 0; j < 8; j++) wp += qp[j] * hif[j];
                    wp = (wp > 0.f) ? wp : NEG_SLOPE * wp;
                    float pa = __expf(wp) * ewB[p];
#pragma unroll
                    for (int j = 0; j < 8; j++) accB[j] += pa * hif[j];
                    spB += pa;
                }
            }
        }

#pragma unroll
        for (int j = 0; j < 8; j++) {
            accA[j] += __shfl_xor(accA[j], 8);
            accA[j] += __shfl_xor(accA[j], 16);
            accA[j] += __shfl_xor(accA[j], 32);
            accB[j] += __shfl_xor(accB[j], 8);
            accB[j] += __shfl_xor(accB[j], 16);
            accB[j] += __shfl_xor(accB[j], 32);
        }
        spA += __shfl_xor(spA, 8); spA += __shfl_xor(spA, 16); spA += __shfl_xor(spA, 32);
        spB += __shfl_xor(spB, 8); spB += __shfl_xor(spB, 16); spB += __shfl_xor(spB, 32);

        if (lane < 8) {
            const float sc = 1.f / ((spA / degA + EPS_F) * degA);
            float4 o0, o1;
            o0.x = fmaxf(accA[0] * sc, 0.f); o0.y = fmaxf(accA[1] * sc, 0.f);
            o0.z = fmaxf(accA[2] * sc, 0.f); o0.w = fmaxf(accA[3] * sc, 0.f);
            o1.x = fmaxf(accA[4] * sc, 0.f); o1.y = fmaxf(accA[5] * sc, 0.f);
            o1.z = fmaxf(accA[6] * sc, 0.f); o1.w = fmaxf(accA[7] * sc, 0.f);
            float* op = out + (size_t)nA * 64 + lane * 8;
            *(float4*)(op) = o0; *(float4*)(op + 4) = o1;
        } else if (lane < 16) {
            const float sc = 1.f / ((spB / degB + EPS_F) * degB);
            float4 o0, o1;
            o0.x = fmaxf(accB[0] * sc, 0.f); o0.y = fmaxf(accB[1] * sc, 0.f);
            o0.z = fmaxf(accB[2] * sc, 0.f); o0.w = fmaxf(accB[3] * sc, 0.f);
            o1.x = fmaxf(accB[4] * sc, 0.f); o1.y = fmaxf(accB[5] * sc, 0.f);
            o1.z = fmaxf(accB[6] * sc, 0.f); o1.w = fmaxf(accB[7] * sc, 0.f);
            float* op = out + (size_t)nB * 64 + (lane - 8) * 8;
            *(float4*)(op) = o0; *(float4*)(op + 4) = o1;
        }
    }
}

extern "C" void kernel_launch(void* const* d_in, const int* in_sizes, int n_in,
                              void* d_out, int out_size, void* d_ws, size_t ws_size,
                              hipStream_t stream) {
    const float* x        = (const float*)d_in[0];
    const float* W_tau    = (const float*)d_in[1];
    const float* query    = (const float*)d_in[2];
    const int*   node_in  = (const int*)d_in[3];
    const int*   node_out = (const int*)d_in[4];
    const int*   relation = (const int*)d_in[5];
    const float* edge_w   = (const float*)d_in[6];
    float* out = (float*)d_out;

    char* ws = (char*)d_ws;
    unsigned short* hiddenb   = (unsigned short*)(ws);                // 57,600,000
    unsigned short* Wb        = (unsigned short*)(ws + 57600000);     //     73,728
    int2*           seg       = (int2*)(ws + 57673728);               //  9,609,216
    int*            subcursor = (int*)(ws + 67282944);                //      3,128

    // W conversion + subcursor zeroing (tiny)
    kprep2<<<(NW / 4 + 255) / 256, 256, 0, stream>>>(W_tau, Wb, subcursor);

    // merged (R23 algorithm, 512-thread blocks): MFMA transform (blocks
    // 0..K1B, resident first) overlapped with two-level fill (K1B..K1B+CHUNKS)
    kbig<<<K1B + CHUNKS, 512, 0, stream>>>(x, Wb, hiddenb, node_in, node_out,
                                           relation, edge_w, subcursor, seg);

    // per-subrange (R23): register-staged physical sort + fused logits/agg/relu
    k3_seg<<<NSUB, 512, 0, stream>>>(hiddenb, query, seg, subcursor, out);
}

// Round 12
// 160.658 us; speedup vs baseline: 1.0643x; 1.0309x over previous
//
#include <hip/hip_runtime.h>
#include <math.h>

#define N_NODES 50000
#define N_EDGES 800000
#define DOUT 64
#define NHEAD 8
#define RP1 9            // num_relations + 1 (self-loop relation id = 8)
#define NEG_SLOPE 0.2f
#define EPS_F 1e-10f
#define M_TOT (N_EDGES + N_NODES)   // 850000 edges incl. self-loops
#define NW (RP1 * DOUT * DOUT)      // 36,864 W elements

// --- two-level bucketing (R23 config) ---
#define SUBSH 6                          // 64 nodes per subrange
#define NSUB ((N_NODES + 63) >> SUBSH)   // 782 subranges
#define SEGCAP 1536                      // lambda=1088, sigma~33
#define EPB 4096                         // per fill chunk
#define CHUNKS ((M_TOT + EPB - 1) / EPB) // 208 fill blocks
#define K1B ((N_NODES + 127) / 128)      // 391 k1 blocks (128 nodes, 8 waves)

typedef __attribute__((ext_vector_type(8))) short bf16x8;
typedef __attribute__((ext_vector_type(4))) float f32x4;

__device__ __forceinline__ unsigned short f2bf(float f) {
    unsigned int u = __float_as_uint(f);
    unsigned int r = (u + 0x7FFFu + ((u >> 16) & 1u)) >> 16;   // RNE
    return (unsigned short)r;
}
__device__ __forceinline__ float bf2f(unsigned short s) {
    return __uint_as_float(((unsigned int)s) << 16);
}

// ===========================================================================
// kprep2: W f32->bf16 + subcursor zeroing only (tiny).
// ===========================================================================
__global__ __launch_bounds__(256) void kprep2(const float* __restrict__ W,
                                              unsigned short* __restrict__ Wb,
                                              int* __restrict__ subcursor) {
    int m = blockIdx.x * 256 + threadIdx.x;
    if (m < NW / 4) {
        int i = m * 4;
        float4 v = *(const float4*)(W + i);
        ushort4 o; o.x = f2bf(v.x); o.y = f2bf(v.y); o.z = f2bf(v.z); o.w = f2bf(v.w);
        *(ushort4*)(Wb + i) = o;
    }
    if (m < NSUB) subcursor[m] = 0;
}

// ===========================================================================
// kbig (R27): structure frozen (R26 pre-commit: fill-chain hypothesis refuted,
// kbig floor ~53us). NEW: the k1 role folds in k3's prologue dots. Right
// after each relation's MFMA result is staged in sw (16 nodes x 64 douts,
// bf16 -- the exact values k3 would re-gather), each lane computes 2 of the
// 128 (node, head) dots  d[n][r*8+h] = sum_j qodd[r][h][j]*hidden[r][n][h*8+j]
// (16 FMA from LDS) and stores a float2 to hout_dots[n][72]. This deletes
// 80 random hiddenb gathers per k3 wave at the cost of 14.4 MB of coalesced
// f32 writes hidden under k1's latency slack.
// ===========================================================================
__global__ __launch_bounds__(512) void kbig(const float* __restrict__ x,
                                            const unsigned short* __restrict__ Wb,
                                            unsigned short* __restrict__ hiddenb,
                                            const int* __restrict__ node_in,
                                            const int* __restrict__ node_out,
                                            const int* __restrict__ relation,
                                            const float* __restrict__ edge_w,
                                            int* __restrict__ subcursor,
                                            int2* __restrict__ seg,
                                            const float* __restrict__ query,
                                            float* __restrict__ hout) {
    __shared__ union SM {
        unsigned short st[8 * 16 * 72];               // k1 role: 18432 B
        struct { int cnt[NSUB]; int base[NSUB]; } f;  // fill role: 6256 B
    } sm;
    __shared__ float qoq[RP1 * 64];                   // q_odd table (k1 role)
    const int t = threadIdx.x;

    if (blockIdx.x >= K1B) {
        // ---------------- fill role (two-level, unchanged) ----------------
        const int chunk = blockIdx.x - K1B;
        const int m0 = chunk * EPB;
        for (int s2 = t; s2 < NSUB; s2 += 512) sm.f.cnt[s2] = 0;
        __syncthreads();
#pragma unroll
        for (int it = 0; it < EPB / 512; it++) {
            int m = m0 + it * 512 + t;
            if (m < M_TOT) {
                int no = (m < N_EDGES) ? node_out[m] : (m - N_EDGES);
                atomicAdd(&sm.f.cnt[no >> SUBSH], 1);
            }
        }
        __syncthreads();
        for (int s2 = t; s2 < NSUB; s2 += 512) {
            int c = sm.f.cnt[s2];
            sm.f.base[s2] = (c > 0) ? atomicAdd(&subcursor[s2], c) : 0;
        }
        __syncthreads();
        for (int s2 = t; s2 < NSUB; s2 += 512) sm.f.cnt[s2] = 0;
        __syncthreads();
#pragma unroll
        for (int it = 0; it < EPB / 512; it++) {
            int m = m0 + it * 512 + t;
            if (m < M_TOT) {
                int no, ni, rl; float ew;
                if (m < N_EDGES) {
                    no = node_out[m]; ni = node_in[m];
                    rl = relation[m]; ew = edge_w[m];
                } else {
                    no = m - N_EDGES; ni = no; rl = RP1 - 1; ew = 1.0f;
                }
                int s2 = no >> SUBSH;
                int r = atomicAdd(&sm.f.cnt[s2], 1);
                int pos = sm.f.base[s2] + r;
                if (pos < SEGCAP) {
                    int2 v;
                    v.x = ni | (rl << 16) | ((no & 63) << 20);
                    v.y = __float_as_int(ew);
                    seg[(size_t)s2 * SEGCAP + pos] = v;
                }
            }
        }
        return;
    }

    // ---------------- k1 (MFMA) role + fused out-side dots ------------------
    // stage q_odd: qoq[(r*8+h)*8 + j] = query[(r*8+h)*16 + 2j+1]
    for (int q = t; q < RP1 * 64; q += 512) {
        qoq[q] = query[(q >> 3) * 16 + 2 * (q & 7) + 1];
    }
    __syncthreads();

    const int bx = blockIdx.x;
    const int wv = t >> 6, lane = t & 63;
    const int quad = lane >> 4, l16 = lane & 15;
    const int base = bx * 128 + wv * 16;

    int arow = base + l16;
    if (arow >= N_NODES) arow = N_NODES - 1;
    const float* xr = x + (size_t)arow * 64 + quad * 8;
    const float4 f0 = *(const float4*)(xr + 0);
    const float4 f1 = *(const float4*)(xr + 4);
    const float4 f2 = *(const float4*)(xr + 32);
    const float4 f3 = *(const float4*)(xr + 36);
    bf16x8 a0, a1;
    a0[0] = (short)f2bf(f0.x); a0[1] = (short)f2bf(f0.y);
    a0[2] = (short)f2bf(f0.z); a0[3] = (short)f2bf(f0.w);
    a0[4] = (short)f2bf(f1.x); a0[5] = (short)f2bf(f1.y);
    a0[6] = (short)f2bf(f1.z); a0[7] = (short)f2bf(f1.w);
    a1[0] = (short)f2bf(f2.x); a1[1] = (short)f2bf(f2.y);
    a1[2] = (short)f2bf(f2.z); a1[3] = (short)f2bf(f2.w);
    a1[4] = (short)f2bf(f3.x); a1[5] = (short)f2bf(f3.y);
    a1[6] = (short)f2bf(f3.z); a1[7] = (short)f2bf(f3.w);

    unsigned short* sw = &sm.st[wv * 16 * 72];

    for (int r = 0; r < RP1; r++) {
        const unsigned short* Wr = Wb + r * 4096;
        f32x4 acc[4];
#pragma unroll
        for (int dt = 0; dt < 4; dt++) {
            const bf16x8 b0 = *(const bf16x8*)(Wr + (dt * 16 + l16) * 64 + quad * 8);
            const bf16x8 b1 = *(const bf16x8*)(Wr + (dt * 16 + l16) * 64 + quad * 8 + 32);
            f32x4 c = {0.f, 0.f, 0.f, 0.f};
            c = __builtin_amdgcn_mfma_f32_16x16x32_bf16(a0, b0, c, 0, 0, 0);
            c = __builtin_amdgcn_mfma_f32_16x16x32_bf16(a1, b1, c, 0, 0, 0);
            acc[dt] = c;
        }
#pragma unroll
        for (int dt = 0; dt < 4; dt++) {
#pragma unroll
            for (int v = 0; v < 4; v++) {
                sw[(quad * 4 + v) * 72 + dt * 16 + l16] = f2bf(acc[dt][v]);
            }
        }
        __threadfence_block();
        // hiddenb store (unchanged)
#pragma unroll
        for (int q = 0; q < 2; q++) {
            int cid = q * 64 + lane;
            int row = cid >> 3;
            int ch = cid & 7;
            int n = base + row;
            if (n < N_NODES) {
                bf16x8 v = *(const bf16x8*)(sw + row * 72 + ch * 8);
                *(bf16x8*)(hiddenb + ((size_t)r * N_NODES + n) * 64 + ch * 8) = v;
            }
        }
        // fused out-side dots: lane -> node nl = lane>>2, heads h0, h0+1
        {
            const int nl = lane >> 2;
            const int h0 = (lane & 3) * 2;
            const unsigned short* hrow = sw + nl * 72;
            const float* q0 = &qoq[(r * 8 + h0) * 8];
            float d0 = 0.f, d1 = 0.f;
#pragma unroll
            for (int j = 0; j < 8; j++) {
                d0 += q0[j]     * bf2f(hrow[h0 * 8 + j]);
                d1 += q0[8 + j] * bf2f(hrow[h0 * 8 + 8 + j]);
            }
            int n = base + nl;
            if (n < N_NODES) {
                *(float2*)(hout + (size_t)n * 72 + r * 8 + h0) = make_float2(d0, d1);
            }
        }
        __threadfence_block();
    }
}

// ===========================================================================
// k3_seg (R27): prologue REPLACED. The 80 random hiddenb gathers + dots per
// wave become one coalesced 576B load per pair (hout_dots rows of nA and nB
// are adjacent: hout[nA*72 .. nA*72+143]). q_odd table and the rel-8 special
// case are deleted. Sort and edge compute unchanged from R23.
// ===========================================================================
__global__ __launch_bounds__(512) void k3_seg(const unsigned short* __restrict__ hiddenb,
                                              const float* __restrict__ query,
                                              const int2* __restrict__ seg,
                                              const int* __restrict__ subcursor,
                                              const float* __restrict__ hout,
                                              float* __restrict__ out) {
    __shared__ float qe[RP1 * 64];
    __shared__ int2  smeta[SEGCAP];
    __shared__ int cnt[64], start[64], cnt2[64];
    __shared__ __align__(16) float bho[8][144];

    const int t = threadIdx.x;
    const int s = blockIdx.x;
    const int scnt = min(subcursor[s], SEGCAP);

    // ---- stage this block's seg entries in registers (early, independent) --
    const int i0 = t, i1 = t + 512, i2 = t + 1024;
    int2 ev0, ev1, ev2;
    if (i0 < scnt) ev0 = seg[(size_t)s * SEGCAP + i0];
    if (i1 < scnt) ev1 = seg[(size_t)s * SEGCAP + i1];
    if (i2 < scnt) ev2 = seg[(size_t)s * SEGCAP + i2];

    for (int q = t; q < RP1 * 64; q += 512) {
        int j = q & 7, rh = q >> 3;
        qe[q] = query[rh * 16 + 2 * j];
    }
    if (t < 64) { cnt[t] = 0; cnt2[t] = 0; }
    __syncthreads();

    if (i0 < scnt) atomicAdd(&cnt[(ev0.x >> 20) & 63], 1);
    if (i1 < scnt) atomicAdd(&cnt[(ev1.x >> 20) & 63], 1);
    if (i2 < scnt) atomicAdd(&cnt[(ev2.x >> 20) & 63], 1);
    __syncthreads();

    if (t < 64) {                       // wave 0: exclusive prefix scan of cnt
        int v = cnt[t];
        int sc = v;
#pragma unroll
        for (int d = 1; d < 64; d <<= 1) {
            int o = __shfl_up(sc, d);
            if (t >= d) sc += o;
        }
        start[t] = sc - v;
    }
    __syncthreads();

    if (i0 < scnt) {
        int nol = (ev0.x >> 20) & 63;
        smeta[start[nol] + atomicAdd(&cnt2[nol], 1)] = ev0;
    }
    if (i1 < scnt) {
        int nol = (ev1.x >> 20) & 63;
        smeta[start[nol] + atomicAdd(&cnt2[nol], 1)] = ev1;
    }
    if (i2 < scnt) {
        int nol = (ev2.x >> 20) & 63;
        smeta[start[nol] + atomicAdd(&cnt2[nol], 1)] = ev2;
    }
    __syncthreads();

    const int wv = t >> 6, lane = t & 63;
    const int e_lo = lane >> 3, h = lane & 7;

    for (int k = 0; k < 4; k++) {
        const int nAl = (k * 8 + wv) * 2, nBl = nAl + 1;
        const int nA = (s << SUBSH) + nAl, nB = nA + 1;
        if (nA >= N_NODES) continue;            // wave-uniform (last subrange)

        // ---- load precomputed out-side dots: 144 contiguous floats (nA,nB) --
        if (lane < 36) {
            float4 v = *(const float4*)(hout + (size_t)nA * 72 + lane * 4);
            *(float4*)(&bho[wv][lane * 4]) = v;
        }
        __threadfence_block();

        const int cA = cnt[nAl], cB = cnt[nBl];
        const int stA = start[nAl], stB = start[nBl];
        const float degA = (float)cA, degB = (float)cB;
        const int cM = (cA > cB) ? cA : cB;

        float accA[8] = {0.f, 0.f, 0.f, 0.f, 0.f, 0.f, 0.f, 0.f};
        float accB[8] = {0.f, 0.f, 0.f, 0.f, 0.f, 0.f, 0.f, 0.f};
        float spA = 0.f, spB = 0.f;

        for (int j0 = 0; j0 < cM; j0 += 32) {
            bf16x8 rA[4], rB[4];
            int relA[4], relB[4]; float ewA[4], ewB[4];
#pragma unroll
            for (int p = 0; p < 4; p++) {
                const int sa = j0 + p * 8 + e_lo;
                if (sa < cA) {
                    int2 mv = smeta[stA + sa];
                    int ni = mv.x & 0xffff;
                    int rl = min((mv.x >> 16) & 15, RP1 - 1);   // defensive clamp
                    relA[p] = rl; ewA[p] = __int_as_float(mv.y);
                    rA[p] = *(const bf16x8*)(hiddenb + ((size_t)(rl * N_NODES + ni)) * 64 + h * 8);
                }
                if (sa < cB) {
                    int2 mv = smeta[stB + sa];
                    int ni = mv.x & 0xffff;
                    int rl = min((mv.x >> 16) & 15, RP1 - 1);   // defensive clamp
                    relB[p] = rl; ewB[p] = __int_as_float(mv.y);
                    rB[p] = *(const bf16x8*)(hiddenb + ((size_t)(rl * N_NODES + ni)) * 64 + h * 8);
                }
            }
#pragma unroll
            for (int p = 0; p < 4; p++) {
                const int sa = j0 + p * 8 + e_lo;
                if (sa < cA) {
                    const float* qp = &qe[(relA[p] * 8 + h) * 8];
                    float hif[8];
#pragma unroll
                    for (int j = 0; j < 8; j++) hif[j] = bf2f((unsigned short)rA[p][j]);
                    float wp = bho[wv][relA[p] * 8 + h];
#pragma unroll
                    for (int j = 0; j < 8; j++) wp += qp[j] * hif[j];
                    wp = (wp > 0.f) ? wp : NEG_SLOPE * wp;
                    float pa = __expf(wp) * ewA[p];
#pragma unroll
                    for (int j = 0; j < 8; j++) accA[j] += pa * hif[j];
                    spA += pa;
                }
                if (sa < cB) {
                    const float* qp = &qe[(relB[p] * 8 + h) * 8];
                    float hif[8];
#pragma unroll
                    for (int j = 0; j < 8; j++) hif[j] = bf2f((unsigned short)rB[p][j]);
                    float wp = bho[wv][72 + relB[p] * 8 + h];
#pragma unroll
                    for (int j = 0; j < 8; j++) wp += qp[j] * hif[j];
                    wp = (wp > 0.f) ? wp : NEG_SLOPE * wp;
                    float pa = __expf(wp) * ewB[p];
#pragma unroll
                    for (int j = 0; j < 8; j++) accB[j] += pa * hif[j];
                    spB += pa;
                }
            }
        }

#pragma unroll
        for (int j = 0; j < 8; j++) {
            accA[j] += __shfl_xor(accA[j], 8);
            accA[j] += __shfl_xor(accA[j], 16);
            accA[j] += __shfl_xor(accA[j], 32);
            accB[j] += __shfl_xor(accB[j], 8);
            accB[j] += __shfl_xor(accB[j], 16);
            accB[j] += __shfl_xor(accB[j], 32);
        }
        spA += __shfl_xor(spA, 8); spA += __shfl_xor(spA, 16); spA += __shfl_xor(spA, 32);
        spB += __shfl_xor(spB, 8); spB += __shfl_xor(spB, 16); spB += __shfl_xor(spB, 32);

        if (lane < 8) {
            const float sc = 1.f / ((spA / degA + EPS_F) * degA);
            float4 o0, o1;
            o0.x = fmaxf(accA[0] * sc, 0.f); o0.y = fmaxf(accA[1] * sc, 0.f);
            o0.z = fmaxf(accA[2] * sc, 0.f); o0.w = fmaxf(accA[3] * sc, 0.f);
            o1.x = fmaxf(accA[4] * sc, 0.f); o1.y = fmaxf(accA[5] * sc, 0.f);
            o1.z = fmaxf(accA[6] * sc, 0.f); o1.w = fmaxf(accA[7] * sc, 0.f);
            float* op = out + (size_t)nA * 64 + lane * 8;
            *(float4*)(op) = o0; *(float4*)(op + 4) = o1;
        } else if (lane < 16) {
            const float sc = 1.f / ((spB / degB + EPS_F) * degB);
            float4 o0, o1;
            o0.x = fmaxf(accB[0] * sc, 0.f); o0.y = fmaxf(accB[1] * sc, 0.f);
            o0.z = fmaxf(accB[2] * sc, 0.f); o0.w = fmaxf(accB[3] * sc, 0.f);
            o1.x = fmaxf(accB[4] * sc, 0.f); o1.y = fmaxf(accB[5] * sc, 0.f);
            o1.z = fmaxf(accB[6] * sc, 0.f); o1.w = fmaxf(accB[7] * sc, 0.f);
            float* op = out + (size_t)nB * 64 + (lane - 8) * 8;
            *(float4*)(op) = o0; *(float4*)(op + 4) = o1;
        }
    }
}

extern "C" void kernel_launch(void* const* d_in, const int* in_sizes, int n_in,
                              void* d_out, int out_size, void* d_ws, size_t ws_size,
                              hipStream_t stream) {
    const float* x        = (const float*)d_in[0];
    const float* W_tau    = (const float*)d_in[1];
    const float* query    = (const float*)d_in[2];
    const int*   node_in  = (const int*)d_in[3];
    const int*   node_out = (const int*)d_in[4];
    const int*   relation = (const int*)d_in[5];
    const float* edge_w   = (const float*)d_in[6];
    float* out = (float*)d_out;

    char* ws = (char*)d_ws;
    unsigned short* hiddenb   = (unsigned short*)(ws);                // 57,600,000
    unsigned short* Wb        = (unsigned short*)(ws + 57600000);     //     73,728
    int2*           seg       = (int2*)(ws + 57673728);               //  9,609,216
    int*            subcursor = (int*)(ws + 67282944);                //      3,128
    float*          hout      = (float*)(ws + 67286080);              // 14,400,000 (16B-aligned)

    // W conversion + subcursor zeroing (tiny)
    kprep2<<<(NW / 4 + 255) / 256, 256, 0, stream>>>(W_tau, Wb, subcursor);

    // merged: MFMA transform + fused out-side dots (blocks 0..K1B) overlapped
    // with two-level fill (K1B..K1B+CHUNKS)
    kbig<<<K1B + CHUNKS, 512, 0, stream>>>(x, Wb, hiddenb, node_in, node_out,
                                           relation, edge_w, subcursor, seg,
                                           query, hout);

    // per-subrange: physical sort + fused logits/agg/relu (prologue = 1 load)
    k3_seg<<<NSUB, 512, 0, stream>>>(hiddenb, query, seg, subcursor, hout, out);
}